// Round 4
// baseline (53.481 us; speedup 1.0000x reference)
//
#include <hip/hip_runtime.h>

#define K_EPS2 1e-8f
#define K_TINY 1e-12f
#define KEY_EDGE_WEIGHT 0.1f

__device__ __forceinline__ float3 f3(float x, float y, float z) { return make_float3(x, y, z); }
__device__ __forceinline__ float3 add3(float3 a, float3 b) { return f3(a.x + b.x, a.y + b.y, a.z + b.z); }
__device__ __forceinline__ float3 sub3(float3 a, float3 b) { return f3(a.x - b.x, a.y - b.y, a.z - b.z); }
__device__ __forceinline__ float3 scl3(float s, float3 a) { return f3(s * a.x, s * a.y, s * a.z); }
__device__ __forceinline__ float dot3(float3 a, float3 b) { return a.x * b.x + a.y * b.y + a.z * b.z; }
__device__ __forceinline__ float3 cross3(float3 a, float3 b) {
    return f3(a.y * b.z - a.z * b.y,
              a.z * b.x - a.x * b.z,
              a.x * b.y - a.y * b.x);
}

// rotate v by unit quaternion (qv, qw):  v + 2*cross(qv, cross(qv, v) + qw*v)
__device__ __forceinline__ float3 qrot(float3 qv, float qw, float3 v) {
    float3 t = add3(cross3(qv, v), scl3(qw, v));
    return add3(v, scl3(2.0f, cross3(qv, t)));
}

// (v,w) = (v1,w1) * (v2,w2)
__device__ __forceinline__ void qmul(float3 v1, float w1, float3 v2, float w2,
                                     float3* v, float* w) {
    *w = w1 * w2 - dot3(v1, v2);
    *v = add3(add3(scl3(w1, v2), scl3(w2, v1)), cross3(v1, v2));
}

__global__ __launch_bounds__(256) void PoseGraph_kernel(
    const float* __restrict__ nodes,   // [N,7]  t(3), q(4) xyzw
    const float* __restrict__ poses,   // [E,4,4] row-major
    const int*   __restrict__ edges,   // [E,2]  int32
    float*       __restrict__ out,     // [E,6]  tau(3), phi(3)
    int E) {
    int e = blockIdx.x * blockDim.x + threadIdx.x;
    if (e >= E) return;

    // ---- edge indices (8B aligned int2 load) ----
    int2 ij = *(const int2*)(edges + (size_t)2 * e);

    // ---- node gathers (L2-resident: node table is 2.8 MB) ----
    const float* pn1 = nodes + (size_t)ij.x * 7;
    const float* pn2 = nodes + (size_t)ij.y * 7;
    float3 t1  = f3(pn1[0], pn1[1], pn1[2]);
    float3 q1v = f3(pn1[3], pn1[4], pn1[5]);
    float  q1w = pn1[6];
    float3 t2  = f3(pn2[0], pn2[1], pn2[2]);
    float3 q2v = f3(pn2[3], pn2[4], pn2[5]);
    float  q2w = pn2[6];

    // ---- relative node transform: q1i = conj(q1) ----
    float3 q1iv = f3(-q1v.x, -q1v.y, -q1v.z);
    float3 t12 = qrot(q1iv, q1w, sub3(t2, t1));
    float3 q12v; float q12w;
    qmul(q1iv, q1w, q2v, q2w, &q12v, &q12w);

    // ---- pose matrix -> (tp, qp), branchless copysign mat2SE3 ----
    const float4* p4 = (const float4*)(poses + (size_t)e * 16);
    float4 r0 = p4[0];
    float4 r1 = p4[1];
    float4 r2 = p4[2];
    float m00 = r0.x, m01 = r0.y, m02 = r0.z;
    float m10 = r1.x, m11 = r1.y, m12 = r1.z;
    float m20 = r2.x, m21 = r2.y, m22 = r2.z;
    float3 tp = f3(r0.w, r1.w, r2.w);

    float qpw = 0.5f * sqrtf(fmaxf(1.0f + m00 + m11 + m22, K_TINY));
    float qpx = ((m21 - m12 >= 0.0f) ? 0.5f : -0.5f) * sqrtf(fmaxf(1.0f + m00 - m11 - m22, K_TINY));
    float qpy = ((m02 - m20 >= 0.0f) ? 0.5f : -0.5f) * sqrtf(fmaxf(1.0f - m00 + m11 - m22, K_TINY));
    float qpz = ((m10 - m01 >= 0.0f) ? 0.5f : -0.5f) * sqrtf(fmaxf(1.0f - m00 - m11 + m22, K_TINY));
    float3 qpv = f3(qpx, qpy, qpz);

    // ---- compose: measured-vs-estimated error transform ----
    float3 te = add3(tp, qrot(qpv, qpw, t12));
    float3 qev; float qew;
    qmul(qpv, qpw, q12v, q12w, &qev, &qew);

    // ---- SO3 log: unit quat -> rotation vector phi ----
    float s = (qew < 0.0f) ? -1.0f : 1.0f;
    float3 v = scl3(s, qev);
    float w = s * qew;
    float nn2 = dot3(v, v);
    float scale;
    if (nn2 > K_EPS2) {
        float n = sqrtf(nn2);                // nn2 > 1e-8 > TINY, clip is a no-op
        scale = 2.0f * atan2f(n, w) / n;
    } else {
        scale = 2.0f / w - 2.0f * nn2 / (3.0f * w * w * w);
    }
    float3 phi = scl3(scale, v);

    // ---- SE3 log tail: V^{-1} * t ----
    float th2 = dot3(phi, phi);
    float coef;
    if (th2 > K_EPS2) {
        float th = sqrtf(th2);               // > TINY, clip no-op
        float half = 0.5f * th;
        float sh = sinf(half);
        float ch = cosf(half);
        coef = (1.0f - half * ch / sh) / th2;
    } else {
        coef = 1.0f / 12.0f + th2 / 720.0f;
    }
    float3 pxt = cross3(phi, te);
    float3 tau = add3(sub3(te, scl3(0.5f, pxt)), scl3(coef, cross3(phi, pxt)));

    // ---- weight (last edge is the key edge) ----
    float wgt = (e == E - 1) ? KEY_EDGE_WEIGHT : 1.0f;

    // ---- store 24B as 3x float2 (e*24 bytes is always 8B-aligned) ----
    float* o = out + (size_t)e * 6;
    *(float2*)(o + 0) = make_float2(tau.x * wgt, tau.y * wgt);
    *(float2*)(o + 2) = make_float2(tau.z * wgt, phi.x * wgt);
    *(float2*)(o + 4) = make_float2(phi.y * wgt, phi.z * wgt);
}

extern "C" void kernel_launch(void* const* d_in, const int* in_sizes, int n_in,
                              void* d_out, int out_size, void* d_ws, size_t ws_size,
                              hipStream_t stream) {
    const float* nodes = (const float*)d_in[0];   // [N,7]
    const float* poses = (const float*)d_in[1];   // [E,4,4]
    const int*   edges = (const int*)d_in[2];     // [E,2] int32 (JAX x64 off)
    float* out = (float*)d_out;

    int E = in_sizes[2] / 2;
    int threads = 256;
    int blocks = (E + threads - 1) / threads;
    PoseGraph_kernel<<<blocks, threads, 0, stream>>>(nodes, poses, edges, out, E);
}